// Round 1
// baseline (902.598 us; speedup 1.0000x reference)
//
#include <hip/hip_runtime.h>

// Problem constants (fixed by setup_inputs)
constexpr int NPTS = 16384;
constexpr int KNB  = 9;
constexpr int CDIM = 16;
constexpr int HDIM = 32;
constexpr int SEG  = 8;                  // candidate-axis segments for occupancy
constexpr int SEG_LEN = NPTS / SEG;      // 2048 candidates per block

// ---------------------------------------------------------------------------
// Register-resident top-9 (smallest d2). Slot arrays only ever indexed with
// compile-time constants -> stay in VGPRs (dynamic indexing would spill to
// scratch). Replace-the-worst + max3-tree rescan; first-match guard avoids
// double-replacement when duplicate worst values exist.
// ---------------------------------------------------------------------------
struct TopK {
    float d[KNB];
    int   id[KNB];
    float dw;   // current worst (max) of the 9

    __device__ __forceinline__ void init() {
#pragma unroll
        for (int s = 0; s < KNB; ++s) { d[s] = 3.0e38f; id[s] = -1; }
        dw = 3.0e38f;
    }

    __device__ __forceinline__ void push(float d2, int j) {
        if (d2 < dw) {          // rare after warm-up; strict < matches JAX
            bool done = false;  // lower-index-wins tie behavior (increasing-j scan)
#pragma unroll
            for (int s = 0; s < KNB; ++s) {
                bool m = (!done) && (d[s] == dw);
                d[s]  = m ? d2 : d[s];
                id[s] = m ? j  : id[s];
                done  = done || m;
            }
            float m0 = fmaxf(fmaxf(d[0], d[1]), d[2]);
            float m1 = fmaxf(fmaxf(d[3], d[4]), d[5]);
            float m2 = fmaxf(fmaxf(d[6], d[7]), d[8]);
            dw = fmaxf(fmaxf(m0, m1), m2);
        }
    }
};

// ---------------------------------------------------------------------------
// kNN partial pass: block = (row-group rg of 256 rows) x (segment sg of 2048
// candidates). Candidates staged in LDS (broadcast reads). Output: per-row,
// per-segment top-9 partial lists.
// ---------------------------------------------------------------------------
__global__ __launch_bounds__(256) void knn_partial(const float* __restrict__ x,
                                                   float* __restrict__ pdist,
                                                   int* __restrict__ pidx) {
    __shared__ float2 tile[SEG_LEN];    // 16 KB

    const int rg  = blockIdx.x & 63;    // 64 row groups
    const int sg  = blockIdx.x >> 6;    // SEG segments
    const int row = rg * 256 + threadIdx.x;

    const float xi = x[row * CDIM + 0];
    const float yi = x[row * CDIM + 1];

    const int base = sg * SEG_LEN;
    for (int t = threadIdx.x; t < SEG_LEN; t += 256) {
        const int j = base + t;
        tile[t] = *reinterpret_cast<const float2*>(x + (size_t)j * CDIM);
    }
    __syncthreads();

    TopK tk; tk.init();
    for (int t = 0; t < SEG_LEN; ++t) {
        const float2 p = tile[t];
        const float dx = xi - p.x;
        const float dy = yi - p.y;
        const float d2 = fmaf(dx, dx, dy * dy);
        tk.push(d2, base + t);
    }

    const int po = (row * SEG + sg) * KNB;
#pragma unroll
    for (int s = 0; s < KNB; ++s) {
        pdist[po + s] = tk.d[s];
        pidx [po + s] = tk.id[s];
    }
}

// ---------------------------------------------------------------------------
// Merge SEG partial lists (8 x 9 = 72 candidates) -> final 9 per row.
// ---------------------------------------------------------------------------
__global__ __launch_bounds__(256) void knn_merge(const float* __restrict__ pdist,
                                                 const int* __restrict__ pidx,
                                                 int* __restrict__ idx) {
    const int row = blockIdx.x * 256 + threadIdx.x;
    const int po  = row * SEG * KNB;

    TopK tk; tk.init();
    for (int t = 0; t < SEG * KNB; ++t) {
        tk.push(pdist[po + t], pidx[po + t]);
    }
#pragma unroll
    for (int s = 0; s < KNB; ++s) idx[row * KNB + s] = tk.id[s];
}

// ---------------------------------------------------------------------------
// One GCN layer: agg = mean_k(hin[idx[n,k]]); out = agg @ W; optional ReLU;
// FINAL fuses x_next = xcur + 1e-4 * out. Thread per node; W broadcast via
// LDS (wave-uniform reads -> conflict-free broadcast).
// ---------------------------------------------------------------------------
template <int CIN, int COUT, bool RELU, bool FINAL>
__global__ __launch_bounds__(256) void gcn_layer(const float* __restrict__ hin,
                                                 const int* __restrict__ idx,
                                                 const float* __restrict__ W,
                                                 const float* __restrict__ xcur,
                                                 float* __restrict__ hout) {
    __shared__ float Ws[CIN * COUT];
    for (int t = threadIdx.x; t < CIN * COUT; t += 256) Ws[t] = W[t];
    __syncthreads();

    const int n = blockIdx.x * 256 + threadIdx.x;

    float agg[CIN];
#pragma unroll
    for (int c = 0; c < CIN; ++c) agg[c] = 0.0f;

#pragma unroll
    for (int k = 0; k < KNB; ++k) {
        const int j = idx[n * KNB + k];
        const float4* r = reinterpret_cast<const float4*>(hin + (size_t)j * CIN);
#pragma unroll
        for (int c4 = 0; c4 < CIN / 4; ++c4) {
            const float4 v = r[c4];
            agg[4 * c4 + 0] += v.x;
            agg[4 * c4 + 1] += v.y;
            agg[4 * c4 + 2] += v.z;
            agg[4 * c4 + 3] += v.w;
        }
    }
    constexpr float inv = 1.0f / 9.0f;
#pragma unroll
    for (int c = 0; c < CIN; ++c) agg[c] *= inv;

#pragma unroll
    for (int o = 0; o < COUT; ++o) {
        float acc = 0.0f;
#pragma unroll
        for (int c = 0; c < CIN; ++c) acc = fmaf(agg[c], Ws[c * COUT + o], acc);
        if (RELU)  acc = fmaxf(acc, 0.0f);
        if (FINAL) acc = xcur[n * COUT + o] + 1e-4f * acc;
        hout[n * COUT + o] = acc;
    }
}

// ---------------------------------------------------------------------------
// Launch: 2 fixed steps (n_steps is always 2; same work every call).
// Workspace layout (stream-ordered lifetimes let hA/hB alias the partials):
//   pdist[N*8*9]f | pidx[N*8*9]i | idx[N*9]i | x1[N*16]f
//   hA = pdist region (2.1MB <= 4.7MB), hB = pidx region.
// ---------------------------------------------------------------------------
extern "C" void kernel_launch(void* const* d_in, const int* in_sizes, int n_in,
                              void* d_out, int out_size, void* d_ws, size_t ws_size,
                              hipStream_t stream) {
    const float* seed = (const float*)d_in[0];
    const float* W1   = (const float*)d_in[1];
    const float* W2   = (const float*)d_in[2];
    const float* W3   = (const float*)d_in[3];
    const float* W4   = (const float*)d_in[4];
    float* out = (float*)d_out;

    char* ws = (char*)d_ws;
    size_t off = 0;
    auto alloc = [&](size_t bytes) -> void* {
        void* p = ws + off;
        off += (bytes + 255) & ~(size_t)255;
        return p;
    };
    float* pdist = (float*)alloc((size_t)NPTS * SEG * KNB * sizeof(float));
    int*   pidx  = (int*)  alloc((size_t)NPTS * SEG * KNB * sizeof(int));
    int*   idx   = (int*)  alloc((size_t)NPTS * KNB * sizeof(int));
    float* x1    = (float*)alloc((size_t)NPTS * CDIM * sizeof(float));
    float* hA    = pdist;            // alias: used only after knn_merge is done
    float* hB    = (float*)pidx;     // alias: ditto

    for (int step = 0; step < 2; ++step) {
        const float* xin  = (step == 0) ? seed : x1;
        float*       xout = (step == 0) ? x1   : out;

        knn_partial<<<64 * SEG, 256, 0, stream>>>(xin, pdist, pidx);
        knn_merge  <<<NPTS / 256, 256, 0, stream>>>(pdist, pidx, idx);

        gcn_layer<CDIM, HDIM, true,  false><<<NPTS / 256, 256, 0, stream>>>(xin, idx, W1, nullptr, hA);
        gcn_layer<HDIM, HDIM, true,  false><<<NPTS / 256, 256, 0, stream>>>(hA,  idx, W2, nullptr, hB);
        gcn_layer<HDIM, HDIM, true,  false><<<NPTS / 256, 256, 0, stream>>>(hB,  idx, W3, nullptr, hA);
        gcn_layer<HDIM, CDIM, false, true ><<<NPTS / 256, 256, 0, stream>>>(hA,  idx, W4, xin, xout);
    }
}